// Round 3
// baseline (1649.802 us; speedup 1.0000x reference)
//
#include <hip/hip_runtime.h>

// LinearAttention: B=16, T=4096, D=512, LR=0.01
//   q,k,v = x @ W^T ; S += LR * sum_b v k^T (before readout) ; out = S q
// Chunked: chunk = 64 time steps = 1024 rows (time-major r = t*16 + b).
// Causality at time-step granularity = 16 rows = one MFMA tile.
//
// R3: every GEMM uses coalesced global->LDS staging (double-buffered,
// 1 barrier per 32-deep K-step) + ds_read_b128 frags. R2's divergent
// per-lane row gathers (16 cache lines per load inst) were the wall.
// out split into scores (causal tile-triangle GEMM, packed into dead
// G/kt regions) + out2 (inter + PV back-to-back staged GEMMs).
//
// MFMA 16x16x32 bf16: D[m][n] = sum_k A[m][k] B[k][n]
//   A-frag: lane(l16,quad) holds A[m=l16][k=quad*8+j]
//   B-frag: lane(l16,quad) holds B[k=quad*8+j][n=l16]
//   C/D   : D[row=quad*4+i][col=l16]

#define LR_ 0.01f

typedef __attribute__((ext_vector_type(8))) short   short8v;
typedef __attribute__((ext_vector_type(4))) float   f32x4;
typedef __attribute__((ext_vector_type(8))) unsigned short us8;

__device__ __forceinline__ unsigned short f2bf(float f) {
    unsigned int u = __float_as_uint(f);
    return (unsigned short)((u + 0x7FFFu + ((u >> 16) & 1u)) >> 16); // RNE
}

// ---------------------------------------------------------------- K0: fp32->bf16
__global__ __launch_bounds__(256) void cvt_kernel(const float* __restrict__ s,
                                                  unsigned short* __restrict__ d, int n) {
    int i = (blockIdx.x * 256 + threadIdx.x) * 8;
    if (i + 8 <= n) {
        f32x4 a = *(const f32x4*)(s + i);
        f32x4 b = *(const f32x4*)(s + i + 4);
        us8 o;
        #pragma unroll
        for (int j = 0; j < 4; j++) { o[j] = f2bf(a[j]); o[j + 4] = f2bf(b[j]); }
        *(us8*)(d + i) = o;
    } else {
        for (; i < n; i++) d[i] = f2bf(s[i]);
    }
}

// ---------------------------------------------------------------- K1: projections
// Tiles over x-rows i (contiguous staging); epilogue scatters to r = t*16+b order.
__global__ __launch_bounds__(256) void proj_kernel(
    const unsigned short* __restrict__ xb, const unsigned short* __restrict__ wb,
    unsigned short* __restrict__ qb, unsigned short* __restrict__ kb,
    unsigned short* __restrict__ kt, unsigned short* __restrict__ vt) {
    __shared__ unsigned short At[2][128][40];   // 32-col K-slab, +8 pad
    __shared__ unsigned short Bt[2][128][40];
    const int n0 = blockIdx.x * 128, i0 = blockIdx.y * 128, mat = blockIdx.z;
    const int tid = threadIdx.x, wid = tid >> 6, lane = tid & 63;
    const int quad = lane >> 4, l16 = lane & 15;
    const int mbase = (wid >> 1) * 64, nbase = (wid & 1) * 64;
    const int srow = tid >> 2, sq8 = (tid & 3) * 8;   // staging: rows srow, srow+64

    const unsigned short* aSrc = xb + (i0 + srow) * 512 + sq8;
    const unsigned short* bSrc = wb + mat * 262144 + (n0 + srow) * 512 + sq8;

    f32x4 acc[4][4];
    #pragma unroll
    for (int a = 0; a < 4; a++)
        #pragma unroll
        for (int b = 0; b < 4; b++) acc[a][b] = (f32x4)0.f;

    us8 ga0 = *(const us8*)(aSrc), ga1 = *(const us8*)(aSrc + 64 * 512);
    us8 gb0 = *(const us8*)(bSrc), gb1 = *(const us8*)(bSrc + 64 * 512);
    *(us8*)&At[0][srow][sq8] = ga0;  *(us8*)&At[0][64 + srow][sq8] = ga1;
    *(us8*)&Bt[0][srow][sq8] = gb0;  *(us8*)&Bt[0][64 + srow][sq8] = gb1;
    __syncthreads();

    #pragma unroll 2
    for (int it = 0; it < 16; ++it) {
        const int cur = it & 1, nxt = cur ^ 1;
        if (it < 15) {
            const int off = (it + 1) * 32;
            ga0 = *(const us8*)(aSrc + off);  ga1 = *(const us8*)(aSrc + 64 * 512 + off);
            gb0 = *(const us8*)(bSrc + off);  gb1 = *(const us8*)(bSrc + 64 * 512 + off);
        }
        short8v a[4], b[4];
        #pragma unroll
        for (int mt = 0; mt < 4; mt++) a[mt] = *(const short8v*)&At[cur][mbase + mt * 16 + l16][quad * 8];
        #pragma unroll
        for (int nt = 0; nt < 4; nt++) b[nt] = *(const short8v*)&Bt[cur][nbase + nt * 16 + l16][quad * 8];
        #pragma unroll
        for (int mt = 0; mt < 4; mt++)
            #pragma unroll
            for (int nt = 0; nt < 4; nt++)
                acc[mt][nt] = __builtin_amdgcn_mfma_f32_16x16x32_bf16(a[mt], b[nt], acc[mt][nt], 0, 0, 0);
        if (it < 15) {
            *(us8*)&At[nxt][srow][sq8] = ga0;  *(us8*)&At[nxt][64 + srow][sq8] = ga1;
            *(us8*)&Bt[nxt][srow][sq8] = gb0;  *(us8*)&Bt[nxt][64 + srow][sq8] = gb1;
        }
        __syncthreads();
    }

    #pragma unroll
    for (int mt = 0; mt < 4; mt++)
        #pragma unroll
        for (int i4 = 0; i4 < 4; i4++) {
            const int irow = i0 + mbase + mt * 16 + quad * 4 + i4;   // x-row b*4096+t
            const int r = ((irow & 4095) << 4) | (irow >> 12);       // r = t*16+b
            #pragma unroll
            for (int nt = 0; nt < 4; nt++) {
                const int e = n0 + nbase + nt * 16 + l16;
                const unsigned short h = f2bf(acc[mt][nt][i4]);
                if (mat == 0) qb[r * 512 + e] = h;
                else if (mat == 1) {
                    kb[r * 512 + e] = h;
                    kt[((r >> 10) * 512 + e) * 1024 + (r & 1023)] = h;
                } else
                    vt[((r >> 10) * 512 + e) * 1024 + (r & 1023)] = h;
            }
        }
}

// ---------------------------------------------------------------- K2: G[c] = sum_r v (x) k
__global__ __launch_bounds__(256) void state_kernel(
    const unsigned short* __restrict__ kt, const unsigned short* __restrict__ vt,
    float* __restrict__ G) {
    __shared__ unsigned short At[2][128][40];
    __shared__ unsigned short Bt[2][128][40];
    const int c = blockIdx.y;
    const int d0 = (blockIdx.x >> 2) * 128, e0 = (blockIdx.x & 3) * 128;
    const int tid = threadIdx.x, wid = tid >> 6, lane = tid & 63;
    const int quad = lane >> 4, l16 = lane & 15;
    const int mbase = (wid >> 1) * 64, nbase = (wid & 1) * 64;
    const int srow = tid >> 2, sq8 = (tid & 3) * 8;

    const unsigned short* aSrc = vt + (size_t)(c * 512 + d0 + srow) * 1024 + sq8;
    const unsigned short* bSrc = kt + (size_t)(c * 512 + e0 + srow) * 1024 + sq8;

    f32x4 acc[4][4];
    #pragma unroll
    for (int a = 0; a < 4; a++)
        #pragma unroll
        for (int b = 0; b < 4; b++) acc[a][b] = (f32x4)0.f;

    us8 ga0 = *(const us8*)(aSrc), ga1 = *(const us8*)(aSrc + 64 * 1024);
    us8 gb0 = *(const us8*)(bSrc), gb1 = *(const us8*)(bSrc + 64 * 1024);
    *(us8*)&At[0][srow][sq8] = ga0;  *(us8*)&At[0][64 + srow][sq8] = ga1;
    *(us8*)&Bt[0][srow][sq8] = gb0;  *(us8*)&Bt[0][64 + srow][sq8] = gb1;
    __syncthreads();

    #pragma unroll 2
    for (int it = 0; it < 32; ++it) {
        const int cur = it & 1, nxt = cur ^ 1;
        if (it < 31) {
            const int off = (it + 1) * 32;
            ga0 = *(const us8*)(aSrc + off);  ga1 = *(const us8*)(aSrc + 64 * 1024 + off);
            gb0 = *(const us8*)(bSrc + off);  gb1 = *(const us8*)(bSrc + 64 * 1024 + off);
        }
        short8v a[4], b[4];
        #pragma unroll
        for (int mt = 0; mt < 4; mt++) a[mt] = *(const short8v*)&At[cur][mbase + mt * 16 + l16][quad * 8];
        #pragma unroll
        for (int nt = 0; nt < 4; nt++) b[nt] = *(const short8v*)&Bt[cur][nbase + nt * 16 + l16][quad * 8];
        #pragma unroll
        for (int mt = 0; mt < 4; mt++)
            #pragma unroll
            for (int nt = 0; nt < 4; nt++)
                acc[mt][nt] = __builtin_amdgcn_mfma_f32_16x16x32_bf16(a[mt], b[nt], acc[mt][nt], 0, 0, 0);
        if (it < 31) {
            *(us8*)&At[nxt][srow][sq8] = ga0;  *(us8*)&At[nxt][64 + srow][sq8] = ga1;
            *(us8*)&Bt[nxt][srow][sq8] = gb0;  *(us8*)&Bt[nxt][64 + srow][sq8] = gb1;
        }
        __syncthreads();
    }

    float* g = G + (size_t)c * 262144;
    #pragma unroll
    for (int mt = 0; mt < 4; mt++)
        #pragma unroll
        for (int nt = 0; nt < 4; nt++)
            #pragma unroll
            for (int i4 = 0; i4 < 4; i4++)
                g[(d0 + mbase + mt * 16 + quad * 4 + i4) * 512 + (e0 + nbase + nt * 16 + l16)] = acc[mt][nt][i4];
}

// ---------------------------------------------------------------- K3: exclusive prefix over chunks
__global__ __launch_bounds__(256) void scan_kernel(const float* __restrict__ G,
                                                   const float* __restrict__ m0,
                                                   unsigned short* __restrict__ Sp) {
    int idx = blockIdx.x * 256 + threadIdx.x;
    float s = m0[idx];
    for (int c = 0; c < 64; c++) {
        Sp[c * 262144 + idx] = f2bf(s);
        s += LR_ * G[c * 262144 + idx];
    }
}

// ---------------------------------------------------------------- K4: scores = LR*(Q K^T), causal tile-triangle
// grid (36, 64): tri-indexed (ti,tj<=ti) 128x128 tiles per chunk. Packed rows:
// band ti base = ti(ti+1)/2*16384 elems, row length 128(ti+1). 16-row masking.
__global__ __launch_bounds__(256) void scores_kernel(
    const unsigned short* __restrict__ qb, const unsigned short* __restrict__ kb,
    unsigned short* __restrict__ Sc0, unsigned short* __restrict__ Sc1) {
    __shared__ unsigned short At[2][128][40];
    __shared__ unsigned short Bt[2][128][40];
    const int c = blockIdx.y;
    int x = blockIdx.x, ti = 0;
    while ((ti + 1) * (ti + 2) / 2 <= x) ++ti;
    const int tj = x - ti * (ti + 1) / 2;
    const int tid = threadIdx.x, wid = tid >> 6, lane = tid & 63;
    const int quad = lane >> 4, l16 = lane & 15;
    const int mbase = (wid >> 1) * 64, nbase = (wid & 1) * 64;
    const int srow = tid >> 2, sq8 = (tid & 3) * 8;

    const unsigned short* aSrc = qb + (c * 1024 + ti * 128 + srow) * 512 + sq8;
    const unsigned short* bSrc = kb + (c * 1024 + tj * 128 + srow) * 512 + sq8;

    f32x4 acc[4][4];
    #pragma unroll
    for (int a = 0; a < 4; a++)
        #pragma unroll
        for (int b = 0; b < 4; b++) acc[a][b] = (f32x4)0.f;

    us8 ga0 = *(const us8*)(aSrc), ga1 = *(const us8*)(aSrc + 64 * 512);
    us8 gb0 = *(const us8*)(bSrc), gb1 = *(const us8*)(bSrc + 64 * 512);
    *(us8*)&At[0][srow][sq8] = ga0;  *(us8*)&At[0][64 + srow][sq8] = ga1;
    *(us8*)&Bt[0][srow][sq8] = gb0;  *(us8*)&Bt[0][64 + srow][sq8] = gb1;
    __syncthreads();

    #pragma unroll 2
    for (int it = 0; it < 16; ++it) {
        const int cur = it & 1, nxt = cur ^ 1;
        if (it < 15) {
            const int off = (it + 1) * 32;
            ga0 = *(const us8*)(aSrc + off);  ga1 = *(const us8*)(aSrc + 64 * 512 + off);
            gb0 = *(const us8*)(bSrc + off);  gb1 = *(const us8*)(bSrc + 64 * 512 + off);
        }
        short8v a[4], b[4];
        #pragma unroll
        for (int mt = 0; mt < 4; mt++) a[mt] = *(const short8v*)&At[cur][mbase + mt * 16 + l16][quad * 8];
        #pragma unroll
        for (int nt = 0; nt < 4; nt++) b[nt] = *(const short8v*)&Bt[cur][nbase + nt * 16 + l16][quad * 8];
        #pragma unroll
        for (int mt = 0; mt < 4; mt++)
            #pragma unroll
            for (int nt = 0; nt < 4; nt++)
                acc[mt][nt] = __builtin_amdgcn_mfma_f32_16x16x32_bf16(a[mt], b[nt], acc[mt][nt], 0, 0, 0);
        if (it < 15) {
            *(us8*)&At[nxt][srow][sq8] = ga0;  *(us8*)&At[nxt][64 + srow][sq8] = ga1;
            *(us8*)&Bt[nxt][srow][sq8] = gb0;  *(us8*)&Bt[nxt][64 + srow][sq8] = gb1;
        }
        __syncthreads();
    }

    unsigned short* scb = (c < 32) ? (Sc0 + (size_t)c * 589824)
                                   : (Sc1 + (size_t)(c - 32) * 589824);
    const int rowlen = (ti + 1) * 128;
    unsigned short* base = scb + ti * (ti + 1) / 2 * 16384 + tj * 128;
    #pragma unroll
    for (int mt = 0; mt < 4; mt++) {
        const int trow = ti * 8 + (wid >> 1) * 4 + mt;
        #pragma unroll
        for (int nt = 0; nt < 4; nt++) {
            const int tcol = tj * 8 + (wid & 1) * 4 + nt;
            const bool keep = (tcol <= trow);
            const int col = nbase + nt * 16 + l16;
            #pragma unroll
            for (int i4 = 0; i4 < 4; i4++) {
                const int rloc = mbase + mt * 16 + quad * 4 + i4;
                base[rloc * rowlen + col] = keep ? f2bf(acc[mt][nt][i4] * LR_) : (unsigned short)0;
            }
        }
    }
}

// ---------------------------------------------------------------- K5: out = Q@Sp^T + Sc@V
// 1024 blocks: c x 8 band-pairs {bp,15-bp} x 2 n-halves. Per band: inter GEMM
// (K=512) then PV GEMM (K=128(ti+1)) sharing acc. M=64, N=256, 4 waves.
__global__ __launch_bounds__(256) void out2_kernel(
    const unsigned short* __restrict__ qb, const unsigned short* __restrict__ Sp,
    const unsigned short* __restrict__ vt,
    const unsigned short* __restrict__ Sc0, const unsigned short* __restrict__ Sc1,
    float* __restrict__ out) {
    __shared__ unsigned short At[2][64][40];
    __shared__ unsigned short Bt[2][256][40];
    const int bx = blockIdx.x;
    const int c  = ((bx >> 7) << 3) | (bx & 7);   // XCD swizzle: chunk in low 3 bits
    const int j  = (bx >> 3) & 15;
    const int bp = j >> 1, nh = j & 1;
    const int tid = threadIdx.x, wid = tid >> 6, lane = tid & 63;
    const int quad = lane >> 4, l16 = lane & 15;
    const int mbase = (wid >> 1) * 32, nbase = (wid & 1) * 128;
    const int srow = tid >> 2, sq8 = (tid & 3) * 8;   // A: 1 slot; B: 4 slots (rows +64k)

    const unsigned short* scb = (c < 32) ? (Sc0 + (size_t)c * 589824)
                                         : (Sc1 + (size_t)(c - 32) * 589824);

    #pragma unroll
    for (int half = 0; half < 2; ++half) {
        const int b  = half ? (15 - bp) : bp;     // 64-row band 0..15
        const int ti = b >> 1;
        const int rowlen = (ti + 1) * 128;        // Sc row length = K_PV
        f32x4 acc[2][8];
        #pragma unroll
        for (int a = 0; a < 2; a++)
            #pragma unroll
            for (int n = 0; n < 8; n++) acc[a][n] = (f32x4)0.f;

        // ======== phase A: inter, K=512 ========
        {
            const unsigned short* aSrc = qb + (c * 1024 + b * 64 + srow) * 512 + sq8;
            const unsigned short* bSrc = Sp + (size_t)c * 262144 + (nh * 256 + srow) * 512 + sq8;
            us8 ga = *(const us8*)(aSrc);
            us8 gb0 = *(const us8*)(bSrc),            gb1 = *(const us8*)(bSrc + 64 * 512);
            us8 gb2 = *(const us8*)(bSrc + 128 * 512), gb3 = *(const us8*)(bSrc + 192 * 512);
            *(us8*)&At[0][srow][sq8] = ga;
            *(us8*)&Bt[0][srow][sq8] = gb0;        *(us8*)&Bt[0][64 + srow][sq8] = gb1;
            *(us8*)&Bt[0][128 + srow][sq8] = gb2;  *(us8*)&Bt[0][192 + srow][sq8] = gb3;
            __syncthreads();
            #pragma unroll 2
            for (int it = 0; it < 16; ++it) {
                const int cur = it & 1, nxt = cur ^ 1;
                if (it < 15) {
                    const int off = (it + 1) * 32;
                    ga  = *(const us8*)(aSrc + off);
                    gb0 = *(const us8*)(bSrc + off);             gb1 = *(const us8*)(bSrc + 64 * 512 + off);
                    gb2 = *(const us8*)(bSrc + 128 * 512 + off); gb3 = *(const us8*)(bSrc + 192 * 512 + off);
                }
                short8v a[2], bb[8];
                #pragma unroll
                for (int mt = 0; mt < 2; mt++) a[mt] = *(const short8v*)&At[cur][mbase + mt * 16 + l16][quad * 8];
                #pragma unroll
                for (int nt = 0; nt < 8; nt++) bb[nt] = *(const short8v*)&Bt[cur][nbase + nt * 16 + l16][quad * 8];
                #pragma unroll
                for (int mt = 0; mt < 2; mt++)
                    #pragma unroll
                    for (int nt = 0; nt < 8; nt++)
                        acc[mt][nt] = __builtin_amdgcn_mfma_f32_16x16x32_bf16(a[mt], bb[nt], acc[mt][nt], 0, 0, 0);
                if (it < 15) {
                    *(us8*)&At[nxt][srow][sq8] = ga;
                    *(us8*)&Bt[nxt][srow][sq8] = gb0;        *(us8*)&Bt[nxt][64 + srow][sq8] = gb1;
                    *(us8*)&Bt[nxt][128 + srow][sq8] = gb2;  *(us8*)&Bt[nxt][192 + srow][sq8] = gb3;
                }
                __syncthreads();
            }
        }

        // ======== phase B: PV, K = rowlen (even # of 32-slabs) ========
        {
            const unsigned short* aSrc = scb + ti * (ti + 1) / 2 * 16384
                                       + ((b & 1) * 64 + srow) * rowlen + sq8;
            const unsigned short* bSrc = vt + (size_t)(c * 512 + nh * 256 + srow) * 1024 + sq8;
            const int itPV = rowlen >> 5;   // 4..32
            us8 ga = *(const us8*)(aSrc);
            us8 gb0 = *(const us8*)(bSrc),             gb1 = *(const us8*)(bSrc + 64 * 1024);
            us8 gb2 = *(const us8*)(bSrc + 128 * 1024), gb3 = *(const us8*)(bSrc + 192 * 1024);
            *(us8*)&At[0][srow][sq8] = ga;
            *(us8*)&Bt[0][srow][sq8] = gb0;        *(us8*)&Bt[0][64 + srow][sq8] = gb1;
            *(us8*)&Bt[0][128 + srow][sq8] = gb2;  *(us8*)&Bt[0][192 + srow][sq8] = gb3;
            __syncthreads();
            #pragma unroll 2
            for (int it = 0; it < itPV; ++it) {
                const int cur = it & 1, nxt = cur ^ 1;
                if (it + 1 < itPV) {
                    const int off = (it + 1) * 32;
                    ga  = *(const us8*)(aSrc + off);
                    gb0 = *(const us8*)(bSrc + off);              gb1 = *(const us8*)(bSrc + 64 * 1024 + off);
                    gb2 = *(const us8*)(bSrc + 128 * 1024 + off); gb3 = *(const us8*)(bSrc + 192 * 1024 + off);
                }
                short8v a[2], bb[8];
                #pragma unroll
                for (int mt = 0; mt < 2; mt++) a[mt] = *(const short8v*)&At[cur][mbase + mt * 16 + l16][quad * 8];
                #pragma unroll
                for (int nt = 0; nt < 8; nt++) bb[nt] = *(const short8v*)&Bt[cur][nbase + nt * 16 + l16][quad * 8];
                #pragma unroll
                for (int mt = 0; mt < 2; mt++)
                    #pragma unroll
                    for (int nt = 0; nt < 8; nt++)
                        acc[mt][nt] = __builtin_amdgcn_mfma_f32_16x16x32_bf16(a[mt], bb[nt], acc[mt][nt], 0, 0, 0);
                if (it + 1 < itPV) {
                    *(us8*)&At[nxt][srow][sq8] = ga;
                    *(us8*)&Bt[nxt][srow][sq8] = gb0;        *(us8*)&Bt[nxt][64 + srow][sq8] = gb1;
                    *(us8*)&Bt[nxt][128 + srow][sq8] = gb2;  *(us8*)&Bt[nxt][192 + srow][sq8] = gb3;
                }
                __syncthreads();
            }
        }

        // ======== epilogue ========
        #pragma unroll
        for (int mt = 0; mt < 2; mt++)
            #pragma unroll
            for (int i4 = 0; i4 < 4; i4++) {
                const int r = c * 1024 + b * 64 + mbase + mt * 16 + quad * 4 + i4;
                float* orow = out + (size_t)(r & 15) * 2097152 + (size_t)(r >> 4) * 512;
                #pragma unroll
                for (int nt = 0; nt < 8; nt++)
                    orow[nh * 256 + nbase + nt * 16 + l16] = acc[mt][nt][i4];
            }
        __syncthreads();   // LDS reuse guard between halves
    }
}

// ---------------------------------------------------------------- launch
extern "C" void kernel_launch(void* const* d_in, const int* in_sizes, int n_in,
                              void* d_out, int out_size, void* d_ws, size_t ws_size,
                              hipStream_t stream) {
    (void)in_sizes; (void)n_in; (void)out_size; (void)ws_size;
    const float* x  = (const float*)d_in[0];
    const float* Wq = (const float*)d_in[1];
    const float* Wk = (const float*)d_in[2];
    const float* Wv = (const float*)d_in[3];
    const float* m0 = (const float*)d_in[4];

    char* w = (char*)d_ws;
    unsigned short* xb = (unsigned short*)(w + 0);            //  64 MB
    unsigned short* wb = (unsigned short*)(w + 67108864);     // 1.5 MB
    unsigned short* qb = (unsigned short*)(w + 68681728);     //  64 MB  [r][e]
    unsigned short* kb = (unsigned short*)(w + 135790592);    //  64 MB  [r][e]
    unsigned short* kt = (unsigned short*)(w + 202899456);    //  64 MB  [c][e][rl]; Sc chunks 32..63 after state
    unsigned short* vt = (unsigned short*)(w + 270008320);    //  64 MB  [c][d][rl]
    float*          G  = (float*)(w + 337117184);             //  64 MB  [c][d][e]; Sc chunks 0..31 after scan
    unsigned short* Sp = (unsigned short*)(w + 404226048);    //  32 MB  [c][d][e]

    unsigned short* Sc0 = (unsigned short*)G;
    unsigned short* Sc1 = kt;

    cvt_kernel<<<16384, 256, 0, stream>>>(x, xb, 33554432);
    cvt_kernel<<<128, 256, 0, stream>>>(Wq, wb, 262144);
    cvt_kernel<<<128, 256, 0, stream>>>(Wk, wb + 262144, 262144);
    cvt_kernel<<<128, 256, 0, stream>>>(Wv, wb + 524288, 262144);

    proj_kernel<<<dim3(4, 512, 3), 256, 0, stream>>>(xb, wb, qb, kb, kt, vt);
    state_kernel<<<dim3(16, 64), 256, 0, stream>>>(kt, vt, G);
    scan_kernel<<<1024, 256, 0, stream>>>(G, m0, Sp);
    scores_kernel<<<dim3(36, 64), 256, 0, stream>>>(qb, kb, Sc0, Sc1);
    out2_kernel<<<1024, 256, 0, stream>>>(qb, Sp, vt, Sc0, Sc1, (float*)d_out);
}